// Round 4
// baseline (153.044 us; speedup 1.0000x reference)
//
#include <hip/hip_runtime.h>

#define NC 2048      // N_CLASSES
#define NB 65536     // BATCH
#define CAP 32       // max parents/children per class on the fast path
#define RPB 32       // rows per block in the main kernel (grid = 2048 = 8 blocks/CU)

// ---------------- reduction helpers ----------------

__device__ inline float wred_sum(float v) {
#pragma unroll
    for (int o = 32; o > 0; o >>= 1) v += __shfl_xor(v, o);
    return v;
}

__device__ inline float wred_max(float v) {
#pragma unroll
    for (int o = 32; o > 0; o >>= 1) v = fmaxf(v, __shfl_xor(v, o));
    return v;
}

// ---------------- transpose H -> HT (2048x2048 f32) ----------------

__global__ __launch_bounds__(256) void hcl_transpose(const float* __restrict__ H,
                                                     float* __restrict__ HT) {
    __shared__ float tile[32][33];
    const int bx = blockIdx.x * 32, by = blockIdx.y * 32;
    const int tx = threadIdx.x, ty = threadIdx.y;  // 32 x 8
#pragma unroll
    for (int i = 0; i < 32; i += 8)
        tile[ty + i][tx] = H[(size_t)(by + ty + i) * NC + bx + tx];
    __syncthreads();
#pragma unroll
    for (int i = 0; i < 32; i += 8)
        HT[(size_t)(bx + ty + i) * NC + by + tx] = tile[tx][ty + i];
}

// ---------------- build per-class index lists (deterministic ballot compaction) ----

__global__ __launch_bounds__(256) void hcl_build(const float* __restrict__ M,
                                                 int* __restrict__ cnt,
                                                 int* __restrict__ idx) {
    const int row  = blockIdx.x * 4 + (threadIdx.x >> 6);
    const int lane = threadIdx.x & 63;
    int count = 0;
#pragma unroll
    for (int k = 0; k < NC / 64; ++k) {
        const int c = k * 64 + lane;
        const float v = M[(size_t)row * NC + c];
        const unsigned long long mask = __ballot(v != 0.0f);
        if (v != 0.0f) {
            const int pos = count + __popcll(mask & ((1ull << lane) - 1ull));
            if (pos < CAP) idx[row * CAP + pos] = c;
        }
        count += __popcll(mask);
    }
    if (lane == 0) cnt[row] = count;
}

// ---------------- main kernel: pipelined 32-row slab per block ----------------

__global__ __launch_bounds__(256) void hcl_row4(
    const float* __restrict__ logits, const int* __restrict__ targets,
    const int* __restrict__ pcnt, const int* __restrict__ ccnt,
    const int* __restrict__ pidx, const int* __restrict__ cidx,
    const float* __restrict__ H, const float* __restrict__ HT,
    float* __restrict__ partial) {
    __shared__ float sExp[NC];   // exp(x_c - m), linear layout
    __shared__ float red[8];     // [0..3] wave maxes, [4..7] wave sums
    const int tid  = threadIdx.x;
    const int w    = tid >> 6, lane = tid & 63;
    const int row0 = blockIdx.x * RPB;

    const float4* L4 = (const float4*)logits;

    // prologue: load first row
    float4 c0 = L4[(size_t)row0 * (NC / 4) + tid];
    float4 c1 = L4[(size_t)row0 * (NC / 4) + 256 + tid];
    int t = targets[row0];

    for (int r = 0; r < RPB; ++r) {
        const int row = row0 + r;

        // ---- issue next row's loads FIRST (a full iteration to land) ----
        float4 n0 = c0, n1 = c1;
        int tn = t;
        if (r + 1 < RPB) {
            n0 = L4[(size_t)(row + 1) * (NC / 4) + tid];
            n1 = L4[(size_t)(row + 1) * (NC / 4) + 256 + tid];
            tn = targets[row + 1];
        }
        // early-issue this row's list metadata/indices (consumed after B2)
        const int cp = pcnt[t], cc = ccnt[t];
        int myi = 0;
        if (tid < 64) myi = (tid < 32) ? pidx[t * CAP + tid] : cidx[t * CAP + (tid - 32)];

        // ---- block max (1 barrier) ----
        float m8 = fmaxf(fmaxf(fmaxf(c0.x, c0.y), fmaxf(c0.z, c0.w)),
                         fmaxf(fmaxf(c1.x, c1.y), fmaxf(c1.z, c1.w)));
        m8 = wred_max(m8);
        if (lane == 0) red[w] = m8;
        __syncthreads();                                        // B1
        const float m = fmaxf(fmaxf(red[0], red[1]), fmaxf(red[2], red[3]));

        // ---- exp + publish to LDS + block sum (1 barrier) ----
        float4 e0, e1;
        e0.x = __expf(c0.x - m); e0.y = __expf(c0.y - m);
        e0.z = __expf(c0.z - m); e0.w = __expf(c0.w - m);
        e1.x = __expf(c1.x - m); e1.y = __expf(c1.y - m);
        e1.z = __expf(c1.z - m); e1.w = __expf(c1.w - m);
        ((float4*)sExp)[tid]       = e0;
        ((float4*)sExp)[tid + 256] = e1;
        float z = e0.x + e0.y + e0.z + e0.w + e1.x + e1.y + e1.z + e1.w;
        z = wred_sum(z);
        if (lane == 0) red[4 + w] = z;
        __syncthreads();                                        // B2 (also publishes sExp)
        const float Z = red[4] + red[5] + red[6] + red[7];

        if (cp <= CAP && cc <= CAP) {
            // ---- sparse gather from LDS: lanes 0-31 parents, 32-63 children ----
            if (tid < 64) {
                float acc = 0.f;
                if (tid < 32) { if (tid < cp)      acc = sExp[myi]; }
                else          { if (tid - 32 < cc) acc = sExp[myi]; }
#pragma unroll
                for (int o = 16; o > 0; o >>= 1) acc += __shfl_xor(acc, o);
                const float PS = __shfl(acc, 0);
                const float CS = __shfl(acc, 32);
                if (tid == 0) {
                    const float xt = logits[(size_t)row * NC + t];  // cache hit
                    const float pt = __expf(xt - m) / Z;
                    const float ce = logf(Z) + (m - xt);            // -log p_t
                    float h = 0.f;
                    if (cp > 0) h += fmaxf(pt - PS / Z, 0.f);
                    if (cc > 0) h += fmaxf(CS / Z - pt, 0.f);
                    partial[row] = ce + h;                          // ALPHA = 1
                }
            }
        } else {
            // ---- dense fallback (block-uniform branch; never taken for this data) ----
            const float4* hr = (const float4*)(H  + (size_t)t * NC);
            const float4* pr = (const float4*)(HT + (size_t)t * NC);
            float4 ha = hr[tid], hb = hr[tid + 256];
            float4 pa = pr[tid], pb = pr[tid + 256];
            float cs = e0.x * ha.x + e0.y * ha.y + e0.z * ha.z + e0.w * ha.w +
                       e1.x * hb.x + e1.y * hb.y + e1.z * hb.z + e1.w * hb.w;
            float ps = e0.x * pa.x + e0.y * pa.y + e0.z * pa.z + e0.w * pa.w +
                       e1.x * pb.x + e1.y * pb.y + e1.z * pb.z + e1.w * pb.w;
            cs = wred_sum(cs);
            ps = wred_sum(ps);
            __syncthreads();            // all readers of red[] for m/Z are done
            if (lane == 0) { red[w] = cs; red[4 + w] = ps; }
            __syncthreads();
            const float CS = red[0] + red[1] + red[2] + red[3];
            const float PS = red[4] + red[5] + red[6] + red[7];
            if (tid == 0) {
                const float xt = logits[(size_t)row * NC + t];
                const float pt = __expf(xt - m) / Z;
                const float ce = logf(Z) + (m - xt);
                float h = 0.f;
                if (cp > 0) h += fmaxf(pt - PS / Z, 0.f);
                if (cc > 0) h += fmaxf(CS / Z - pt, 0.f);
                partial[row] = ce + h;
            }
        }

        __syncthreads();                                        // B3: sExp/red reuse next iter
        c0 = n0; c1 = n1; t = tn;
    }
}

// ---------------- legacy fallback row kernel (small-ws paths) ----------------

template <int MODE>  // 1: write partials; 2: atomic into out
__global__ __launch_bounds__(256) void hcl_row_kernel(
    const float* __restrict__ logits, const int* __restrict__ targets,
    const float* __restrict__ H, float* __restrict__ partial, float* __restrict__ out) {
    const int wid  = threadIdx.x >> 6;
    const int lane = threadIdx.x & 63;
    const int row  = blockIdx.x * 4 + wid;

    const float*  lrow  = logits + (size_t)row * NC;
    const float4* lrow4 = (const float4*)lrow;
    float4 v[8];
#pragma unroll
    for (int k = 0; k < 8; ++k) v[k] = lrow4[lane + 64 * k];
    const int t = targets[row];

    float m = fmaxf(fmaxf(v[0].x, v[0].y), fmaxf(v[0].z, v[0].w));
#pragma unroll
    for (int k = 1; k < 8; ++k)
        m = fmaxf(m, fmaxf(fmaxf(v[k].x, v[k].y), fmaxf(v[k].z, v[k].w)));
    m = wred_max(m);

    float z = 0.f;
#pragma unroll
    for (int k = 0; k < 8; ++k)
        z += __expf(v[k].x - m) + __expf(v[k].y - m) +
             __expf(v[k].z - m) + __expf(v[k].w - m);
    const float Z = wred_sum(z);

    const float4* hr4 = (const float4*)(H + (size_t)t * NC);
    float cs = 0.f, hcs = 0.f, ps = 0.f, hps = 0.f;
#pragma unroll
    for (int k = 0; k < 8; ++k) {
        const float4 h4 = hr4[lane + 64 * k];
        const float e0 = __expf(v[k].x - m), e1 = __expf(v[k].y - m);
        const float e2 = __expf(v[k].z - m), e3 = __expf(v[k].w - m);
        cs  += e0 * h4.x + e1 * h4.y + e2 * h4.z + e3 * h4.w;
        hcs += h4.x + h4.y + h4.z + h4.w;
        const size_t c0 = 4 * (size_t)(lane + 64 * k);
        const float p0 = H[(c0 + 0) * NC + t], p1 = H[(c0 + 1) * NC + t];
        const float p2 = H[(c0 + 2) * NC + t], p3 = H[(c0 + 3) * NC + t];
        ps  += e0 * p0 + e1 * p1 + e2 * p2 + e3 * p3;
        hps += p0 + p1 + p2 + p3;
    }
    const float CS  = wred_sum(cs);
    const float HCS = wred_sum(hcs);
    const float PS  = wred_sum(ps);
    const float HPS = wred_sum(hps);

    if (lane == 0) {
        const float xt = lrow[t];
        const float pt = __expf(xt - m) / Z;
        const float ce = logf(Z) + (m - xt);
        float h = 0.f;
        if (HPS > 0.f) h += fmaxf(pt - PS / Z, 0.f);
        if (HCS > 0.f) h += fmaxf(CS / Z - pt, 0.f);
        const float val = ce + h;
        if (MODE == 2) atomicAdd(out, val * (1.0f / NB));
        else           partial[row] = val;
    }
}

// ---------------- final reduction (two deterministic stages) ----------------

__global__ __launch_bounds__(1024) void hcl_final1(const float* __restrict__ partial,
                                                   double* __restrict__ partial2) {
    __shared__ double sm[16];
    double acc = (double)partial[blockIdx.x * 1024 + threadIdx.x];
#pragma unroll
    for (int o = 32; o > 0; o >>= 1) acc += __shfl_xor(acc, o);
    const int wid = threadIdx.x >> 6, lane = threadIdx.x & 63;
    if (lane == 0) sm[wid] = acc;
    __syncthreads();
    if (threadIdx.x == 0) {
        double s = 0.0;
#pragma unroll
        for (int i = 0; i < 16; i++) s += sm[i];
        partial2[blockIdx.x] = s;
    }
}

__global__ __launch_bounds__(64) void hcl_final2(const double* __restrict__ partial2,
                                                 float* __restrict__ out) {
    double acc = partial2[threadIdx.x];
#pragma unroll
    for (int o = 32; o > 0; o >>= 1) acc += __shfl_xor(acc, o);
    if (threadIdx.x == 0) out[0] = (float)(acc / (double)NB);
}

__global__ __launch_bounds__(1024) void hcl_final_single(const float* __restrict__ partial,
                                                         float* __restrict__ out) {
    __shared__ double sm[16];
    double acc = 0.0;
    for (int i = threadIdx.x; i < NB; i += 1024) acc += (double)partial[i];
#pragma unroll
    for (int o = 32; o > 0; o >>= 1) acc += __shfl_xor(acc, o);
    const int wid = threadIdx.x >> 6, lane = threadIdx.x & 63;
    if (lane == 0) sm[wid] = acc;
    __syncthreads();
    if (threadIdx.x == 0) {
        double s = 0.0;
        for (int i = 0; i < 16; i++) s += sm[i];
        out[0] = (float)(s / (double)NB);
    }
}

// ---------------- launch ----------------

extern "C" void kernel_launch(void* const* d_in, const int* in_sizes, int n_in,
                              void* d_out, int out_size, void* d_ws, size_t ws_size,
                              hipStream_t stream) {
    const float* logits  = (const float*)d_in[0];
    const int*   targets = (const int*)d_in[1];
    const float* H       = (const float*)d_in[2];
    float* out = (float*)d_out;

    // fast-path workspace layout
    size_t off = 0;
    float*  HT       = (float*)d_ws;                 off += (size_t)NC * NC * 4;  // 16 MB
    float*  partial  = (float*)((char*)d_ws + off);  off += (size_t)NB * 4;       // 256 KB
    double* partial2 = (double*)((char*)d_ws + off); off += 64 * 8;
    int*    pcnt     = (int*)((char*)d_ws + off);    off += NC * 4;
    int*    ccnt     = (int*)((char*)d_ws + off);    off += NC * 4;
    int*    pidx     = (int*)((char*)d_ws + off);    off += (size_t)NC * CAP * 4;
    int*    cidx     = (int*)((char*)d_ws + off);    off += (size_t)NC * CAP * 4;
    const size_t NEED_FAST = off;
    const size_t NEED_PART = (size_t)NB * sizeof(float);

    if (ws_size >= NEED_FAST) {
        hcl_transpose<<<dim3(64, 64), dim3(32, 8), 0, stream>>>(H, HT);
        hcl_build<<<NC / 4, 256, 0, stream>>>(H,  ccnt, cidx);   // children(r): nonzero cols of row r
        hcl_build<<<NC / 4, 256, 0, stream>>>(HT, pcnt, pidx);   // parents(c):  nonzero rows of col c
        hcl_row4<<<NB / RPB, 256, 0, stream>>>(logits, targets, pcnt, ccnt, pidx, cidx, H, HT, partial);
        hcl_final1<<<64, 1024, 0, stream>>>(partial, partial2);
        hcl_final2<<<1, 64, 0, stream>>>(partial2, out);
    } else if (ws_size >= NEED_PART) {
        float* part = (float*)d_ws;
        hcl_row_kernel<1><<<NB / 4, 256, 0, stream>>>(logits, targets, H, part, out);
        hcl_final_single<<<1, 1024, 0, stream>>>(part, out);
    } else {
        hipMemsetAsync(d_out, 0, sizeof(float), stream);
        hcl_row_kernel<2><<<NB / 4, 256, 0, stream>>>(logits, targets, H, nullptr, out);
    }
}